// Round 3
// baseline (19243.665 us; speedup 1.0000x reference)
//
#include <hip/hip_runtime.h>
#include <cstdint>

#define NBATCH 16
#define NPOINT 1024
#define NPTS   100000
#define GPB    16            // blocks per batch
#define TPB    256           // threads per block (4 waves)
#define WPB    4
#define NAG    64            // agents (waves) per batch = GPB * WPB
#define NSUB   16            // sub-blocks per batch in precompute kernels
#define STRIDE (GPB * TPB)   // 4096 threads per batch
#define KPT    25            // points per thread
#define NPAIR  13            // KPT as float pairs (last half-padded)
#define FAST_TRIES (1 << 17) // ~13 ms worth of L2 polls: unreachable in a legit same-XCD wait

typedef unsigned long long u64;
typedef unsigned int u32;

// d_ws layout — IDENTICAL footprint to the last PASSING round (ends at 24576 B exactly;
// the failed round extended past 24 KB, a suspected ws overflow):
//   @0     : float psum[16][16][4]  (4 KB)  — per-(batch,sub) partial coord sums
//   @4096  : uint  pmax[16][16]     (1 KB)  — per-(batch,sub) partial max sq-radius
//   @8192  : u64   slots[2][16][64] (16 KB) — per-(parity,batch,agent) argmax msg;
//                                             zeroed by max_kernel block 0 each launch
//                                             (stale seq would false-accept: clear mandatory)

// ---------------- precompute 1: per-(batch,sub) coordinate sums ----------------
__global__ __launch_bounds__(256) void sum_kernel(const float* __restrict__ xyz,
                                                  float* __restrict__ psum) {
    const int b   = blockIdx.x & 15;
    const int sub = blockIdx.x >> 4;          // 0..15
    const float* P = xyz + (size_t)b * NPTS * 3;
    float sx = 0.f, sy = 0.f, sz = 0.f;
    for (int i = sub * TPB + threadIdx.x; i < NPTS; i += NSUB * TPB) {
        sx += P[i * 3 + 0];
        sy += P[i * 3 + 1];
        sz += P[i * 3 + 2];
    }
    #pragma unroll
    for (int off = 32; off; off >>= 1) {
        sx += __shfl_xor(sx, off);
        sy += __shfl_xor(sy, off);
        sz += __shfl_xor(sz, off);
    }
    __shared__ float r[3][4];
    const int wave = threadIdx.x >> 6, lane = threadIdx.x & 63;
    if (lane == 0) { r[0][wave] = sx; r[1][wave] = sy; r[2][wave] = sz; }
    __syncthreads();
    if (threadIdx.x == 0) {
        float* o = psum + (b * NSUB + sub) * 4;
        o[0] = r[0][0] + r[0][1] + r[0][2] + r[0][3];
        o[1] = r[1][0] + r[1][1] + r[1][2] + r[1][3];
        o[2] = r[2][0] + r[2][1] + r[2][2] + r[2][3];
    }
}

// -------- precompute 2: per-(batch,sub) max squared radius + slot clear --------
__global__ __launch_bounds__(256) void max_kernel(const float* __restrict__ xyz,
                                                  const float* __restrict__ psum,
                                                  unsigned* __restrict__ pmax,
                                                  u64* __restrict__ slots) {
    if (blockIdx.x == 0) {                    // clear the 2048 message slots (8 per thread)
        #pragma unroll
        for (int k = 0; k < 8; ++k) slots[threadIdx.x + 256 * k] = 0ull;
    }
    const int b   = blockIdx.x & 15;
    const int sub = blockIdx.x >> 4;
    const float* P = xyz + (size_t)b * NPTS * 3;
    float sx = 0.f, sy = 0.f, sz = 0.f;
    #pragma unroll
    for (int s = 0; s < NSUB; ++s) {          // fixed order: deterministic mean for all blocks
        sx += psum[(b * NSUB + s) * 4 + 0];
        sy += psum[(b * NSUB + s) * 4 + 1];
        sz += psum[(b * NSUB + s) * 4 + 2];
    }
    const float mx = sx / (float)NPTS, my = sy / (float)NPTS, mz = sz / (float)NPTS;
    float best = 0.f;
    for (int i = sub * TPB + threadIdx.x; i < NPTS; i += NSUB * TPB) {
        float dx = P[i * 3 + 0] - mx;
        float dy = P[i * 3 + 1] - my;
        float dz = P[i * 3 + 2] - mz;
        best = fmaxf(best, dx * dx + dy * dy + dz * dz);
    }
    #pragma unroll
    for (int off = 32; off; off >>= 1) best = fmaxf(best, __shfl_xor(best, off));
    __shared__ float r[4];
    const int wave = threadIdx.x >> 6, lane = threadIdx.x & 63;
    if (lane == 0) r[wave] = best;
    __syncthreads();
    if (threadIdx.x == 0)
        pmax[b * NSUB + sub] = __float_as_uint(fmaxf(fmaxf(r[0], r[1]), fmaxf(r[2], r[3])));
}

// ---- DPP wave-max for u64 keys: row_shr 1/2/4/8 + row_bcast 15/31 → lane 63 holds max ----
// (validated bit-exact in round 1)
__device__ __forceinline__ u64 wave_max_u64(u64 k) {
    u32 lo = (u32)k, hi = (u32)(k >> 32);
    #define DPP_STEP(CTRL) do {                                                          \
        u32 olo = (u32)__builtin_amdgcn_update_dpp((int)lo, (int)lo, CTRL, 0xf, 0xf, false); \
        u32 ohi = (u32)__builtin_amdgcn_update_dpp((int)hi, (int)hi, CTRL, 0xf, 0xf, false); \
        u64 oo = ((u64)ohi << 32) | olo;                                                 \
        u64 cc = ((u64)hi  << 32) | lo;                                                  \
        if (oo > cc) { lo = olo; hi = ohi; }                                             \
    } while (0)
    DPP_STEP(0x111);   // row_shr:1
    DPP_STEP(0x112);   // row_shr:2
    DPP_STEP(0x114);   // row_shr:4
    DPP_STEP(0x118);   // row_shr:8  -> lanes 15/31/47/63 hold their row max
    DPP_STEP(0x142);   // row_bcast:15 -> lane 31 = max(0..31), lane 63 = max(32..63)
    DPP_STEP(0x143);   // row_bcast:31 -> lane 63 = max(0..63)
    #undef DPP_STEP
    return ((u64)hi << 32) | lo;
}

__device__ __forceinline__ u64 bcast_lane63(u64 v) {
    u32 lo = (u32)__builtin_amdgcn_readlane((int)(u32)v, 63);
    u32 hi = (u32)__builtin_amdgcn_readlane((int)(u32)(v >> 32), 63);
    return ((u64)hi << 32) | lo;
}

// ---- L2-scope primitives: sc0 = bypass L1, served by the per-XCD L2 ----
__device__ __forceinline__ void store_u64_sc0(u64* p, u64 v) {
    asm volatile("global_store_dwordx2 %0, %1, off sc0" :: "v"(p), "v"(v) : "memory");
}
__device__ __forceinline__ u64 load_u64_sc0(u64* p) {
    u64 v;
    asm volatile("global_load_dwordx2 %0, %1, off sc0\n\t"
                 "s_waitcnt vmcnt(0)"
                 : "=v"(v) : "v"(p) : "memory");
    return v;
}
__device__ __forceinline__ void store_agent(u64* p, u64 v) {
    __hip_atomic_store(p, v, __ATOMIC_RELAXED, __HIP_MEMORY_SCOPE_AGENT);
}
__device__ __forceinline__ u64 load_agent(u64* p) {
    return __hip_atomic_load(p, __ATOMIC_RELAXED, __HIP_MEMORY_SCOPE_AGENT);
}

// ---------------- main: FPS loop, wave-autonomous agents, scope-escalating comm --------
// Message word: [63:54] seq (=i+1), [53:22] float bits of max distance (>=0),
//               [21:0]  0x3FFFFF - idx (max-compare => smallest index on ties = np.argmax).
// Parity double-buffer, lag<=1 (64 agents): an agent storing seq i+3 (same parity as i+1)
// finished its i+1 poll => all agents stored i+2 => all finished the i+1 poll; so a poller
// at iteration i only ever observes seq <= i-1 (stale) or exactly i+1. Seq-gating makes
// stale observations harmless at ANY scope, so scope selection is a liveness/perf concern
// only, never a correctness one.
//
// Scope protocol (deadlock-free under any block->XCD mapping):
//   - every agent stores its msg sc0 (local XCD L2).
//   - fast poll = sc0 loads, BOUNDED tries. Expected path: all 16 blocks of a batch are
//     blockIdx ≡ b (mod 8) -> same XCD under round-robin -> poll is L2-local (~250 cy).
//   - after a successful fast poll: deferred agent-scope backup store of the same msg
//     (identical bits -> benign), draining during the next compute phase.
//   - on timeout (2^17 tries ~ 13 ms, impossible legitimately): store agent-scope NOW,
//     demote permanently -> dual-store + agent-scope poll (round-1-proven behavior).
__global__ __launch_bounds__(256, 1) void fps_kernel(const float* __restrict__ xyz,
                                                     const float* __restrict__ cmap,
                                                     const int* __restrict__ init_far,
                                                     const unsigned* __restrict__ pmax,
                                                     u64* __restrict__ slots,
                                                     float* __restrict__ out) {
    const int b   = blockIdx.x & 15;   // batch (16 blocks of a batch expected on XCD b%8)
    const int g   = blockIdx.x >> 4;   // block-in-batch 0..15
    const int tid = threadIdx.x;
    const int wave = tid >> 6, lane = tid & 63;
    const int ag  = g * WPB + wave;    // agent id 0..63 within batch
    const int tl  = g * TPB + tid;     // batch-local lane 0..4095
    const float* P = xyz + (size_t)b * NPTS * 3;

    // s_obj: deterministic reduce over the 16 partial maxes
    float m0 = 0.f;
    #pragma unroll
    for (int s = 0; s < NSUB; ++s) m0 = fmaxf(m0, __uint_as_float(pmax[b * NSUB + s]));
    const float sb = sqrtf(m0);

    // register-resident points (pairs, SLP-vectorizes to v_pk_* fp32) + running distances
    float pxx[NPAIR], pxy[NPAIR], pyx[NPAIR], pyy[NPAIR],
          pzx[NPAIR], pzy[NPAIR], pdx[NPAIR], pdy[NPAIR];
    #pragma unroll
    for (int j = 0; j < NPAIR; ++j) {
        const int p0 = tl + (2 * j) * STRIDE;
        const int p1 = tl + (2 * j + 1) * STRIDE;
        const bool v0 = p0 < NPTS, v1 = p1 < NPTS;
        pxx[j] = v0 ? P[p0 * 3 + 0] : 0.f;  pxy[j] = v1 ? P[p1 * 3 + 0] : 0.f;
        pyx[j] = v0 ? P[p0 * 3 + 1] : 0.f;  pyy[j] = v1 ? P[p1 * 3 + 1] : 0.f;
        pzx[j] = v0 ? P[p0 * 3 + 2] : 0.f;  pzy[j] = v1 ? P[p1 * 3 + 2] : 0.f;
        pdx[j] = v0 ? 1e10f : -1.0f;        pdy[j] = v1 ? 1e10f : -1.0f;
        // every lane owns >=24 valid points -> per-lane best always >= 0
    }

    __shared__ int curhist[NPOINT];    // every block records the full selection history

    int cur = init_far[b];
    float cx = P[cur * 3 + 0], cy = P[cur * 3 + 1], cz = P[cur * 3 + 2];
    bool demoted = false;

    for (int i = 0; i < NPOINT; ++i) {
        if (tid == 192) curhist[i] = cur;          // wave 3 lane 0, LDS only
        if (i == NPOINT - 1) break;

        // ---- distance update + per-lane argmax (exact fp order match: no fma/contract) ----
        float best = -1.0f;
        int bidx = 0;
        {
            #pragma clang fp contract(off)
            #pragma unroll
            for (int j = 0; j < NPAIR; ++j) {
                float dx0 = pxx[j] - cx, dx1 = pxy[j] - cx;
                float dy0 = pyx[j] - cy, dy1 = pyy[j] - cy;
                float dz0 = pzx[j] - cz, dz1 = pzy[j] - cz;
                float s0 = dx0 * dx0 + dy0 * dy0;  float s1 = dx1 * dx1 + dy1 * dy1;
                s0 = s0 + dz0 * dz0;               s1 = s1 + dz1 * dz1;
                float n0 = fminf(pdx[j], s0);      float n1 = fminf(pdy[j], s1);
                pdx[j] = n0;                       pdy[j] = n1;
                if (n0 > best) { best = n0; bidx = tl + (2 * j) * STRIDE; }      // strict >
                if (n1 > best) { best = n1; bidx = tl + (2 * j + 1) * STRIDE; }  // => first max
            }
        }

        // ---- wave argmax via DPP; lane 63 holds this agent's message ----
        const u64 want = (u64)(i + 1);
        u64 key = ((u64)__float_as_uint(best) << 22) | (u64)(0x3FFFFFu - (unsigned)bidx);
        const u64 msg = wave_max_u64(key) | (want << 54);   // valid on lane 63 only

        u64* const bs = slots + ((size_t)(i & 1) * NBATCH + b) * NAG;
        if (lane == 63) {
            store_u64_sc0(&bs[ag], msg);
            if (demoted) store_agent(&bs[ag], msg);   // demoted: immediate backup
        }

        // ---- poll: 64 slots (512 B) read one-per-lane, single coalesced load/round ----
        u64 v;
        bool have = false;
        if (!demoted) {
            int tries = 0;
            for (;;) {
                v = load_u64_sc0(&bs[lane]);
                if (__all((v >> 54) >= want)) { have = true; break; }
                if (++tries > FAST_TRIES) break;            // uniform across the wave
                if ((tries & 255) == 255) __builtin_amdgcn_s_sleep(1);
            }
            if (!have) {                                    // escalate, permanently
                if (lane == 63) store_agent(&bs[ag], msg);
                demoted = true;
            }
        }
        if (!have) {
            int tries = 0;
            for (;;) {
                v = load_agent(&bs[lane]);
                if (__all((v >> 54) >= want)) break;
                if (++tries > 16) __builtin_amdgcn_s_sleep(1);
            }
        }

        // ---- global argmax over the 64 agent keys (seq bits uniform = want) ----
        u64 w = bcast_lane63(wave_max_u64(v));
        cur = (int)(0x3FFFFFu - (unsigned)(w & 0x3FFFFFu));
        cx = P[cur * 3 + 0];   // broadcast gather (L2-hot: batch xyz = 1.2 MB < 4 MB XCD L2)
        cy = P[cur * 3 + 1];
        cz = P[cur * 3 + 2];

        // deferred agent-scope backup (feeds any later-demoting poller); drains under the
        // next iteration's compute phase, off the critical path
        if (!demoted && lane == 63) store_agent(&bs[ag], msg);
    }

    // ---------------- deferred output pass: 64 rows per block ----------------
    __syncthreads();                   // waves converge; curhist fully written
    if (tid < 64) {
        const int row = g * 64 + tid;  // 16 blocks x 64 rows = 1024
        const int c   = curhist[row];
        const float cm = cmap[(size_t)b * NPTS + c];
        const float x = P[c * 3 + 0], y = P[c * 3 + 1], z = P[c * 3 + 2];
        float* o = out + ((size_t)b * NPOINT + row) * 4;
        o[0] = cm;
        o[1] = x / sb;
        o[2] = y / sb;
        o[3] = z / sb;
    }
}

extern "C" void kernel_launch(void* const* d_in, const int* in_sizes, int n_in,
                              void* d_out, int out_size, void* d_ws, size_t ws_size,
                              hipStream_t stream) {
    const float* mesh = (const float*)d_in[0];
    const float* cmap = (const float*)d_in[1];
    const int* init   = (const int*)d_in[2];
    float* out = (float*)d_out;

    char* ws      = (char*)d_ws;
    float* psum   = (float*)ws;
    unsigned* pmx = (unsigned*)(ws + 4096);
    u64* slots    = (u64*)(ws + 8192);

    sum_kernel<<<dim3(256), dim3(TPB), 0, stream>>>(mesh, psum);
    max_kernel<<<dim3(256), dim3(TPB), 0, stream>>>(mesh, psum, pmx, slots);
    fps_kernel<<<dim3(256), dim3(TPB), 0, stream>>>(mesh, cmap, init, pmx, slots, out);
}

// Round 4
// 2123.571 us; speedup vs baseline: 9.0619x; 9.0619x over previous
//
#include <hip/hip_runtime.h>
#include <cstdint>

#define NBATCH 16
#define NPOINT 1024
#define NPTS   100000
#define GPB    16            // blocks per batch
#define TPB    256           // threads per block (4 waves)
#define WPB    4
#define NSUB   16            // sub-blocks per batch in precompute kernels
#define STRIDE (GPB * TPB)   // 4096 threads per batch
#define KPT    25            // points per thread
#define NPAIR  13            // KPT as float pairs (last half-padded)
#define FAST_TRIES 8192      // ~1.2 ms of L2 polls; unreachable for a legit same-XCD wait

typedef unsigned long long u64;
typedef unsigned int u32;

// d_ws layout (24576 B total, proven size):
//   @0     : float psum[16][16][4]  (4 KB) — per-(batch,sub) partial coord sums
//   @4096  : uint  pmax[16][16]     (1 KB) — per-(batch,sub) partial max sq-radius
//   @8192  : u64   fast[2][16][16]  (4 KB) — L2-atomic channel; one 128-B line per
//                                            (parity,batch) — never shares a line with slow
//   @12288 : u64   slow[2][16][16]  (4 KB) — LLC (agent-scope) backup channel
//   @16384 : spare (8 KB)           — both channels zeroed by max_kernel block 0
//                                     (stale seq would false-accept: clear mandatory)

// ---------------- precompute 1: per-(batch,sub) coordinate sums ----------------
__global__ __launch_bounds__(256) void sum_kernel(const float* __restrict__ xyz,
                                                  float* __restrict__ psum) {
    const int b   = blockIdx.x & 15;
    const int sub = blockIdx.x >> 4;          // 0..15
    const float* P = xyz + (size_t)b * NPTS * 3;
    float sx = 0.f, sy = 0.f, sz = 0.f;
    for (int i = sub * TPB + threadIdx.x; i < NPTS; i += NSUB * TPB) {
        sx += P[i * 3 + 0];
        sy += P[i * 3 + 1];
        sz += P[i * 3 + 2];
    }
    #pragma unroll
    for (int off = 32; off; off >>= 1) {
        sx += __shfl_xor(sx, off);
        sy += __shfl_xor(sy, off);
        sz += __shfl_xor(sz, off);
    }
    __shared__ float r[3][4];
    const int wave = threadIdx.x >> 6, lane = threadIdx.x & 63;
    if (lane == 0) { r[0][wave] = sx; r[1][wave] = sy; r[2][wave] = sz; }
    __syncthreads();
    if (threadIdx.x == 0) {
        float* o = psum + (b * NSUB + sub) * 4;
        o[0] = r[0][0] + r[0][1] + r[0][2] + r[0][3];
        o[1] = r[1][0] + r[1][1] + r[1][2] + r[1][3];
        o[2] = r[2][0] + r[2][1] + r[2][2] + r[2][3];
    }
}

// -------- precompute 2: per-(batch,sub) max squared radius + slot clear --------
__global__ __launch_bounds__(256) void max_kernel(const float* __restrict__ xyz,
                                                  const float* __restrict__ psum,
                                                  unsigned* __restrict__ pmax,
                                                  u64* __restrict__ slots) {
    if (blockIdx.x == 0) {                    // clear 16 KB of channel slots (8 u64/thread)
        #pragma unroll
        for (int k = 0; k < 8; ++k) slots[threadIdx.x + 256 * k] = 0ull;
    }
    const int b   = blockIdx.x & 15;
    const int sub = blockIdx.x >> 4;
    const float* P = xyz + (size_t)b * NPTS * 3;
    float sx = 0.f, sy = 0.f, sz = 0.f;
    #pragma unroll
    for (int s = 0; s < NSUB; ++s) {          // fixed order: deterministic mean for all blocks
        sx += psum[(b * NSUB + s) * 4 + 0];
        sy += psum[(b * NSUB + s) * 4 + 1];
        sz += psum[(b * NSUB + s) * 4 + 2];
    }
    const float mx = sx / (float)NPTS, my = sy / (float)NPTS, mz = sz / (float)NPTS;
    float best = 0.f;
    for (int i = sub * TPB + threadIdx.x; i < NPTS; i += NSUB * TPB) {
        float dx = P[i * 3 + 0] - mx;
        float dy = P[i * 3 + 1] - my;
        float dz = P[i * 3 + 2] - mz;
        best = fmaxf(best, dx * dx + dy * dy + dz * dz);
    }
    #pragma unroll
    for (int off = 32; off; off >>= 1) best = fmaxf(best, __shfl_xor(best, off));
    __shared__ float r[4];
    const int wave = threadIdx.x >> 6, lane = threadIdx.x & 63;
    if (lane == 0) r[wave] = best;
    __syncthreads();
    if (threadIdx.x == 0)
        pmax[b * NSUB + sub] = __float_as_uint(fmaxf(fmaxf(r[0], r[1]), fmaxf(r[2], r[3])));
}

// ---- DPP wave-max for u64 keys: row_shr 1/2/4/8 + row_bcast 15/31 → lane 63 holds max ----
// (validated bit-exact in round 1; bound_ctrl=false keeps own value on invalid source,
//  max(self,self)=self so edges are safe; zero-filled lanes lose to any tagged key)
__device__ __forceinline__ u64 wave_max_u64(u64 k) {
    u32 lo = (u32)k, hi = (u32)(k >> 32);
    #define DPP_STEP(CTRL) do {                                                          \
        u32 olo = (u32)__builtin_amdgcn_update_dpp((int)lo, (int)lo, CTRL, 0xf, 0xf, false); \
        u32 ohi = (u32)__builtin_amdgcn_update_dpp((int)hi, (int)hi, CTRL, 0xf, 0xf, false); \
        u64 oo = ((u64)ohi << 32) | olo;                                                 \
        u64 cc = ((u64)hi  << 32) | lo;                                                  \
        if (oo > cc) { lo = olo; hi = ohi; }                                             \
    } while (0)
    DPP_STEP(0x111);   // row_shr:1
    DPP_STEP(0x112);   // row_shr:2
    DPP_STEP(0x114);   // row_shr:4
    DPP_STEP(0x118);   // row_shr:8  -> lanes 15/31/47/63 hold their row max
    DPP_STEP(0x142);   // row_bcast:15 -> lane 31 = max(0..31), lane 63 = max(32..63)
    DPP_STEP(0x143);   // row_bcast:31 -> lane 63 = max(0..63)
    #undef DPP_STEP
    return ((u64)hi << 32) | lo;
}

__device__ __forceinline__ u64 bcast_lane63(u64 v) {
    u32 lo = (u32)__builtin_amdgcn_readlane((int)(u32)v, 63);
    u32 hi = (u32)__builtin_amdgcn_readlane((int)(u32)(v >> 32), 63);
    return ((u64)hi << 32) | lo;
}

// ---- L2-executed atomic primitives (no sc1 => executed at the LOCAL XCD L2) ----
// Atomic RMWs are never served by L1, so the poller cannot spin on a stale L1 line
// (the failure mode of the previous round's sc0 plain-load poll).
__device__ __forceinline__ void atomic_swap_l2(u64* p, u64 v) {
    asm volatile("global_atomic_swap_x2 %0, %1, off" :: "v"(p), "v"(v) : "memory");
}
__device__ __forceinline__ u64 atomic_read_l2(u64* p) {
    u64 ret, zero = 0;
    asm volatile("global_atomic_add_x2 %0, %1, %2, off sc0\n\t"
                 "s_waitcnt vmcnt(0)"
                 : "=v"(ret) : "v"(p), "v"(zero) : "memory");
    return ret;
}

// ---------------- main: FPS loop ----------------
// Message word: [63:54] seq (=i+1), [53:22] float bits of max distance (>=0),
//               [21:0]  0x3FFFFF - idx (max-compare => smallest index on ties = np.argmax).
// Topology: 16 block-level agents per batch (R0's traffic level). Intra-block wave->block
// key gathering and winner broadcast use seq-tagged LDS spins (no __syncthreads in loop).
// Cross-block: parity double-buffer, lag<=1 (proof as in round 1, 16 agents); seq-gating
// makes stale observations harmless at ANY scope, so channel choice is liveness/perf only.
// Dual-channel publish (separate cache lines!): L2 swap (fast) + agent-scope store (slow).
// Fast pollers use L2 atomic-reads with a bounded budget, then demote permanently to the
// slow channel. Separate lines mean a dirty fast-line eviction can never clobber a newer
// slow-line value at the LLC => the fallback is deadlock-free under any block->XCD mapping.
__global__ __launch_bounds__(256, 1) void fps_kernel(const float* __restrict__ xyz,
                                                     const float* __restrict__ cmap,
                                                     const int* __restrict__ init_far,
                                                     const unsigned* __restrict__ pmax,
                                                     u64* __restrict__ fastc,
                                                     u64* __restrict__ slowc,
                                                     float* __restrict__ out) {
    const int b   = blockIdx.x & 15;   // batch (16 blocks expected on XCD b%8 by round-robin)
    const int g   = blockIdx.x >> 4;   // block-in-batch 0..15
    const int tid = threadIdx.x;
    const int wave = tid >> 6, lane = tid & 63;
    const int tl  = g * TPB + tid;     // batch-local lane 0..4095
    const float* P = xyz + (size_t)b * NPTS * 3;

    // s_obj: deterministic reduce over the 16 partial maxes
    float m0 = 0.f;
    #pragma unroll
    for (int s = 0; s < NSUB; ++s) m0 = fmaxf(m0, __uint_as_float(pmax[b * NSUB + s]));
    const float sb = sqrtf(m0);

    // register-resident points (pairs, SLP-vectorizes to v_pk_* fp32) + running distances
    float pxx[NPAIR], pxy[NPAIR], pyx[NPAIR], pyy[NPAIR],
          pzx[NPAIR], pzy[NPAIR], pdx[NPAIR], pdy[NPAIR];
    #pragma unroll
    for (int j = 0; j < NPAIR; ++j) {
        const int p0 = tl + (2 * j) * STRIDE;
        const int p1 = tl + (2 * j + 1) * STRIDE;
        const bool v0 = p0 < NPTS, v1 = p1 < NPTS;
        pxx[j] = v0 ? P[p0 * 3 + 0] : 0.f;  pxy[j] = v1 ? P[p1 * 3 + 0] : 0.f;
        pyx[j] = v0 ? P[p0 * 3 + 1] : 0.f;  pyy[j] = v1 ? P[p1 * 3 + 1] : 0.f;
        pzx[j] = v0 ? P[p0 * 3 + 2] : 0.f;  pzy[j] = v1 ? P[p1 * 3 + 2] : 0.f;
        pdx[j] = v0 ? 1e10f : -1.0f;        pdy[j] = v1 ? 1e10f : -1.0f;
        // every lane owns >=24 valid points -> per-lane best always >= 0
    }

    __shared__ u64 lkey[WPB];          // seq-tagged per-wave keys
    __shared__ u64 pub;                // seq-tagged winner broadcast
    __shared__ int curhist[NPOINT];    // full selection history (every block)
    if (tid == 0) { pub = 0; }
    if (tid < WPB) lkey[tid] = 0;
    __syncthreads();                   // one-time arming barrier (outside the loop)

    int cur = init_far[b];
    float cx = P[cur * 3 + 0], cy = P[cur * 3 + 1], cz = P[cur * 3 + 2];
    bool demoted = false;

    for (int i = 0; i < NPOINT; ++i) {
        if (tid == 192) curhist[i] = cur;          // wave 3 lane 0, LDS only
        if (i == NPOINT - 1) break;

        // ---- distance update + per-lane argmax (exact fp order match: no fma/contract) ----
        float best = -1.0f;
        int bidx = 0;
        {
            #pragma clang fp contract(off)
            #pragma unroll
            for (int j = 0; j < NPAIR; ++j) {
                float dx0 = pxx[j] - cx, dx1 = pxy[j] - cx;
                float dy0 = pyx[j] - cy, dy1 = pyy[j] - cy;
                float dz0 = pzx[j] - cz, dz1 = pzy[j] - cz;
                float s0 = dx0 * dx0 + dy0 * dy0;  float s1 = dx1 * dx1 + dy1 * dy1;
                s0 = s0 + dz0 * dz0;               s1 = s1 + dz1 * dz1;
                float n0 = fminf(pdx[j], s0);      float n1 = fminf(pdy[j], s1);
                pdx[j] = n0;                       pdy[j] = n1;
                if (n0 > best) { best = n0; bidx = tl + (2 * j) * STRIDE; }      // strict >
                if (n1 > best) { best = n1; bidx = tl + (2 * j + 1) * STRIDE; }  // => first max
            }
        }

        // ---- wave argmax via DPP; tagged wave key published to LDS ----
        const u64 want = (u64)(i + 1);
        u64 key = ((u64)__float_as_uint(best) << 22) | (u64)(0x3FFFFFu - (unsigned)bidx);
        const u64 wkey = wave_max_u64(key) | (want << 54);   // valid on lane 63
        if (lane == 63)
            __hip_atomic_store(&lkey[wave], wkey, __ATOMIC_RELAXED,
                               __HIP_MEMORY_SCOPE_WORKGROUP);

        u64* const fs = fastc + ((size_t)(i & 1) * NBATCH + b) * GPB;  // 128-B line
        u64* const ss = slowc + ((size_t)(i & 1) * NBATCH + b) * GPB;  // 128-B line

        if (wave == 0) {
            // gather the 4 wave keys (seq-tagged LDS spin; intra-block lag<=1 => <= want)
            u64 k;
            for (;;) {
                k = (lane < WPB)
                    ? __hip_atomic_load(&lkey[lane], __ATOMIC_RELAXED,
                                        __HIP_MEMORY_SCOPE_WORKGROUP)
                    : (want << 54);
                if (__all((int)((k >> 54) >= want))) break;
            }
            const u64 bk = wave_max_u64(lane < WPB ? k : 0);   // lane63 = block key (tagged)
            if (lane == 63) {
                atomic_swap_l2(&fs[g], bk);                    // local-XCD L2 channel
                __hip_atomic_store(&ss[g], bk, __ATOMIC_RELAXED,
                                   __HIP_MEMORY_SCOPE_AGENT);  // LLC backup channel
            }

            // poll the 16 block slots, one per lane
            u64 v = 0;
            bool ok = false;
            if (!demoted) {
                int tries = 0;
                for (;;) {
                    u64 r = 0;
                    if (lane < GPB) r = atomic_read_l2(&fs[lane]);
                    const u64 gate = (lane < GPB) ? r : ~0ull;
                    v = (lane < GPB) ? r : 0;
                    if (__all((int)((gate >> 54) >= want))) { ok = true; break; }
                    if (++tries > FAST_TRIES) break;               // uniform decision
                    if ((tries & 63) == 63) __builtin_amdgcn_s_sleep(1);
                }
                if (!ok) demoted = true;                           // permanent
            }
            if (!ok) {
                int tries = 0;
                for (;;) {
                    const u64 r = (lane < GPB)
                        ? __hip_atomic_load(&ss[lane], __ATOMIC_RELAXED,
                                            __HIP_MEMORY_SCOPE_AGENT)
                        : ~0ull;
                    v = (lane < GPB) ? r : 0;
                    if (__all((int)((r >> 54) >= want))) break;
                    if (++tries > 16) __builtin_amdgcn_s_sleep(1);
                }
            }

            // global argmax over the 16 block keys; publish to the other waves
            const u64 w = bcast_lane63(wave_max_u64(v));
            if (lane == 0)
                __hip_atomic_store(&pub, w, __ATOMIC_RELAXED,
                                   __HIP_MEMORY_SCOPE_WORKGROUP);
            cur = (int)(0x3FFFFFu - (unsigned)(w & 0x3FFFFFu));
        } else {
            // waves 1-3: spin on the seq-tagged LDS publish (no barrier)
            int tries = 0;
            u64 pv;
            for (;;) {
                pv = __hip_atomic_load(&pub, __ATOMIC_RELAXED,
                                       __HIP_MEMORY_SCOPE_WORKGROUP);
                if ((pv >> 54) >= want) break;
                if (++tries > 64) __builtin_amdgcn_s_sleep(1);
            }
            cur = (int)(0x3FFFFFu - (unsigned)(pv & 0x3FFFFFu));
        }

        cx = P[cur * 3 + 0];   // broadcast gather (batch xyz = 1.2 MB, XCD-L2-hot)
        cy = P[cur * 3 + 1];
        cz = P[cur * 3 + 2];
    }

    // ---------------- deferred output pass: 64 rows per block ----------------
    __syncthreads();                   // waves converge; curhist fully written
    if (tid < 64) {
        const int row = g * 64 + tid;  // 16 blocks x 64 rows = 1024
        const int c   = curhist[row];
        const float cm = cmap[(size_t)b * NPTS + c];
        const float x = P[c * 3 + 0], y = P[c * 3 + 1], z = P[c * 3 + 2];
        float* o = out + ((size_t)b * NPOINT + row) * 4;
        o[0] = cm;
        o[1] = x / sb;
        o[2] = y / sb;
        o[3] = z / sb;
    }
}

extern "C" void kernel_launch(void* const* d_in, const int* in_sizes, int n_in,
                              void* d_out, int out_size, void* d_ws, size_t ws_size,
                              hipStream_t stream) {
    const float* mesh = (const float*)d_in[0];
    const float* cmap = (const float*)d_in[1];
    const int* init   = (const int*)d_in[2];
    float* out = (float*)d_out;

    char* ws      = (char*)d_ws;
    float* psum   = (float*)ws;
    unsigned* pmx = (unsigned*)(ws + 4096);
    u64* slots    = (u64*)(ws + 8192);   // covers both channels (16 KB cleared)
    u64* fastc    = (u64*)(ws + 8192);
    u64* slowc    = (u64*)(ws + 12288);

    sum_kernel<<<dim3(256), dim3(TPB), 0, stream>>>(mesh, psum);
    max_kernel<<<dim3(256), dim3(TPB), 0, stream>>>(mesh, psum, pmx, slots);
    fps_kernel<<<dim3(256), dim3(TPB), 0, stream>>>(mesh, cmap, init, pmx, fastc, slowc, out);
}

// Round 5
// 1970.275 us; speedup vs baseline: 9.7670x; 1.0778x over previous
//
#include <hip/hip_runtime.h>
#include <cstdint>

#define NBATCH 16
#define NPOINT 1024
#define NPTS   100000
#define GPB    16            // blocks per batch
#define TPB    256           // threads per block (4 waves)
#define WPB    4
#define NSUB   16            // sub-blocks per batch in precompute kernels
#define STRIDE (GPB * TPB)   // 4096 threads per batch
#define KPT    25            // points per thread
#define NPAIR  13            // KPT as float pairs (last half-padded)

typedef unsigned long long u64;
typedef unsigned int u32;

// d_ws layout (24576 B total, proven size):
//   @0     : float psum[16][16][4]  (4 KB) — per-(batch,sub) partial coord sums
//   @4096  : uint  pmax[16][16]     (1 KB) — per-(batch,sub) partial max sq-radius
//   @8192  : u64   slots[2][16][16] (4 KB) — per-(parity,batch,block) argmax msg;
//                                            one 128-B line per (parity,batch);
//                                            zeroed by max_kernel block 0 (stale seq would
//                                            false-accept: clear mandatory)

// ---------------- precompute 1: per-(batch,sub) coordinate sums ----------------
__global__ __launch_bounds__(256) void sum_kernel(const float* __restrict__ xyz,
                                                  float* __restrict__ psum) {
    const int b   = blockIdx.x & 15;
    const int sub = blockIdx.x >> 4;          // 0..15
    const float* P = xyz + (size_t)b * NPTS * 3;
    float sx = 0.f, sy = 0.f, sz = 0.f;
    for (int i = sub * TPB + threadIdx.x; i < NPTS; i += NSUB * TPB) {
        sx += P[i * 3 + 0];
        sy += P[i * 3 + 1];
        sz += P[i * 3 + 2];
    }
    #pragma unroll
    for (int off = 32; off; off >>= 1) {
        sx += __shfl_xor(sx, off);
        sy += __shfl_xor(sy, off);
        sz += __shfl_xor(sz, off);
    }
    __shared__ float r[3][4];
    const int wave = threadIdx.x >> 6, lane = threadIdx.x & 63;
    if (lane == 0) { r[0][wave] = sx; r[1][wave] = sy; r[2][wave] = sz; }
    __syncthreads();
    if (threadIdx.x == 0) {
        float* o = psum + (b * NSUB + sub) * 4;
        o[0] = r[0][0] + r[0][1] + r[0][2] + r[0][3];
        o[1] = r[1][0] + r[1][1] + r[1][2] + r[1][3];
        o[2] = r[2][0] + r[2][1] + r[2][2] + r[2][3];
    }
}

// -------- precompute 2: per-(batch,sub) max squared radius + slot clear --------
__global__ __launch_bounds__(256) void max_kernel(const float* __restrict__ xyz,
                                                  const float* __restrict__ psum,
                                                  unsigned* __restrict__ pmax,
                                                  u64* __restrict__ slots) {
    if (blockIdx.x == 0) {                    // clear the 512 message slots (2 per thread)
        slots[threadIdx.x] = 0ull;
        slots[threadIdx.x + 256] = 0ull;
    }
    const int b   = blockIdx.x & 15;
    const int sub = blockIdx.x >> 4;
    const float* P = xyz + (size_t)b * NPTS * 3;
    float sx = 0.f, sy = 0.f, sz = 0.f;
    #pragma unroll
    for (int s = 0; s < NSUB; ++s) {          // fixed order: deterministic mean for all blocks
        sx += psum[(b * NSUB + s) * 4 + 0];
        sy += psum[(b * NSUB + s) * 4 + 1];
        sz += psum[(b * NSUB + s) * 4 + 2];
    }
    const float mx = sx / (float)NPTS, my = sy / (float)NPTS, mz = sz / (float)NPTS;
    float best = 0.f;
    for (int i = sub * TPB + threadIdx.x; i < NPTS; i += NSUB * TPB) {
        float dx = P[i * 3 + 0] - mx;
        float dy = P[i * 3 + 1] - my;
        float dz = P[i * 3 + 2] - mz;
        best = fmaxf(best, dx * dx + dy * dy + dz * dz);
    }
    #pragma unroll
    for (int off = 32; off; off >>= 1) best = fmaxf(best, __shfl_xor(best, off));
    __shared__ float r[4];
    const int wave = threadIdx.x >> 6, lane = threadIdx.x & 63;
    if (lane == 0) r[wave] = best;
    __syncthreads();
    if (threadIdx.x == 0)
        pmax[b * NSUB + sub] = __float_as_uint(fmaxf(fmaxf(r[0], r[1]), fmaxf(r[2], r[3])));
}

// ---- DPP wave-max for u64 keys: row_shr 1/2/4/8 + row_bcast 15/31 → lane 63 holds max ----
// (validated bit-exact in rounds 1/3/4)
__device__ __forceinline__ u64 wave_max_u64(u64 k) {
    u32 lo = (u32)k, hi = (u32)(k >> 32);
    #define DPP_STEP(CTRL) do {                                                          \
        u32 olo = (u32)__builtin_amdgcn_update_dpp((int)lo, (int)lo, CTRL, 0xf, 0xf, false); \
        u32 ohi = (u32)__builtin_amdgcn_update_dpp((int)hi, (int)hi, CTRL, 0xf, 0xf, false); \
        u64 oo = ((u64)ohi << 32) | olo;                                                 \
        u64 cc = ((u64)hi  << 32) | lo;                                                  \
        if (oo > cc) { lo = olo; hi = ohi; }                                             \
    } while (0)
    DPP_STEP(0x111);   // row_shr:1
    DPP_STEP(0x112);   // row_shr:2
    DPP_STEP(0x114);   // row_shr:4
    DPP_STEP(0x118);   // row_shr:8  -> lanes 15/31/47/63 hold their row max
    DPP_STEP(0x142);   // row_bcast:15 -> lane 31 = max(0..31), lane 63 = max(32..63)
    DPP_STEP(0x143);   // row_bcast:31 -> lane 63 = max(0..63)
    #undef DPP_STEP
    return ((u64)hi << 32) | lo;
}

__device__ __forceinline__ u64 bcast_lane63(u64 v) {
    u32 lo = (u32)__builtin_amdgcn_readlane((int)(u32)v, 63);
    u32 hi = (u32)__builtin_amdgcn_readlane((int)(u32)(v >> 32), 63);
    return ((u64)hi << 32) | lo;
}

__device__ __forceinline__ void store_agent(u64* p, u64 v) {
    __hip_atomic_store(p, v, __ATOMIC_RELAXED, __HIP_MEMORY_SCOPE_AGENT);
}
__device__ __forceinline__ u64 load_agent(u64* p) {
    return __hip_atomic_load(p, __ATOMIC_RELAXED, __HIP_MEMORY_SCOPE_AGENT);
}

// ---------------- main: FPS loop ----------------
// Message word: [63:54] seq (=i+1), [53:22] float bits of max distance (>=0),
//               [21:0]  0x3FFFFF - idx (max-compare => smallest index on ties = np.argmax).
// Topology (R0-proven traffic level): 16 block agents per batch, agent-scope (LLC) comm.
// Intra-block: seq-tagged LDS spins instead of per-iteration __syncthreads (R4-proven).
// Cross-block: parity double-buffer, lag<=1 — an agent storing seq i+3 (same parity as
// i+1) finished its i+2 poll => all agents stored i+2 => all finished the i+1 poll; so a
// poller at iteration i only ever observes seq <= i-1 (stale, rejected) or exactly i+1.
//
// KEY CHANGE this round: amdgpu_waves_per_eu(1,1). The kernel carries 104 loop-resident
// floats/lane (8 arrays x NPAIR); with the default occupancy-targeting register budget the
// compiler was spilling them to scratch (VGPR_Count=76 < 104 across ALL previous rounds),
// costing an L2 round-trip of ~500B/lane every iteration. We run exactly 1 wave/EU
// (256 blocks x 4 waves on 256 CUs), so allocating for 1 wave/EU is free.
__global__ void
__attribute__((amdgpu_flat_work_group_size(256, 256), amdgpu_waves_per_eu(1, 1)))
fps_kernel(const float* __restrict__ xyz,
           const float* __restrict__ cmap,
           const int* __restrict__ init_far,
           const unsigned* __restrict__ pmax,
           u64* __restrict__ slots,
           float* __restrict__ out) {
    const int b   = blockIdx.x & 15;   // batch
    const int g   = blockIdx.x >> 4;   // block-in-batch 0..15
    const int tid = threadIdx.x;
    const int wave = tid >> 6, lane = tid & 63;
    const int tl  = g * TPB + tid;     // batch-local lane 0..4095
    const float* P = xyz + (size_t)b * NPTS * 3;

    // s_obj: deterministic reduce over the 16 partial maxes
    float m0 = 0.f;
    #pragma unroll
    for (int s = 0; s < NSUB; ++s) m0 = fmaxf(m0, __uint_as_float(pmax[b * NSUB + s]));
    const float sb = sqrtf(m0);

    // register-resident points (pairs, SLP-vectorizes to v_pk_* fp32) + running distances
    float pxx[NPAIR], pxy[NPAIR], pyx[NPAIR], pyy[NPAIR],
          pzx[NPAIR], pzy[NPAIR], pdx[NPAIR], pdy[NPAIR];
    #pragma unroll
    for (int j = 0; j < NPAIR; ++j) {
        const int p0 = tl + (2 * j) * STRIDE;
        const int p1 = tl + (2 * j + 1) * STRIDE;
        const bool v0 = p0 < NPTS, v1 = p1 < NPTS;
        pxx[j] = v0 ? P[p0 * 3 + 0] : 0.f;  pxy[j] = v1 ? P[p1 * 3 + 0] : 0.f;
        pyx[j] = v0 ? P[p0 * 3 + 1] : 0.f;  pyy[j] = v1 ? P[p1 * 3 + 1] : 0.f;
        pzx[j] = v0 ? P[p0 * 3 + 2] : 0.f;  pzy[j] = v1 ? P[p1 * 3 + 2] : 0.f;
        pdx[j] = v0 ? 1e10f : -1.0f;        pdy[j] = v1 ? 1e10f : -1.0f;
        // every lane owns >=24 valid points -> per-lane best always >= 0
    }

    __shared__ u64 lkey[WPB];          // seq-tagged per-wave keys
    __shared__ u64 pub;                // seq-tagged winner broadcast
    __shared__ int curhist[NPOINT];    // full selection history (every block)
    if (tid == 0) pub = 0;
    if (tid < WPB) lkey[tid] = 0;
    __syncthreads();                   // one-time arming barrier (outside the loop)

    int cur = init_far[b];
    float cx = P[cur * 3 + 0], cy = P[cur * 3 + 1], cz = P[cur * 3 + 2];

    for (int i = 0; i < NPOINT; ++i) {
        if (tid == 192) curhist[i] = cur;          // wave 3 lane 0, LDS only
        if (i == NPOINT - 1) break;

        // ---- distance update + per-lane argmax (exact fp order match: no fma/contract) ----
        float best = -1.0f;
        int bidx = 0;
        {
            #pragma clang fp contract(off)
            #pragma unroll
            for (int j = 0; j < NPAIR; ++j) {
                float dx0 = pxx[j] - cx, dx1 = pxy[j] - cx;
                float dy0 = pyx[j] - cy, dy1 = pyy[j] - cy;
                float dz0 = pzx[j] - cz, dz1 = pzy[j] - cz;
                float s0 = dx0 * dx0 + dy0 * dy0;  float s1 = dx1 * dx1 + dy1 * dy1;
                s0 = s0 + dz0 * dz0;               s1 = s1 + dz1 * dz1;
                float n0 = fminf(pdx[j], s0);      float n1 = fminf(pdy[j], s1);
                pdx[j] = n0;                       pdy[j] = n1;
                if (n0 > best) { best = n0; bidx = tl + (2 * j) * STRIDE; }      // strict >
                if (n1 > best) { best = n1; bidx = tl + (2 * j + 1) * STRIDE; }  // => first max
            }
        }

        // ---- wave argmax via DPP; tagged wave key published to LDS ----
        const u64 want = (u64)(i + 1);
        u64 key = ((u64)__float_as_uint(best) << 22) | (u64)(0x3FFFFFu - (unsigned)bidx);
        const u64 wkey = wave_max_u64(key) | (want << 54);   // valid on lane 63
        if (lane == 63)
            __hip_atomic_store(&lkey[wave], wkey, __ATOMIC_RELAXED,
                               __HIP_MEMORY_SCOPE_WORKGROUP);

        u64* const bs = slots + ((size_t)(i & 1) * NBATCH + b) * GPB;  // 128-B line

        if (wave == 0) {
            // gather the 4 wave keys (seq-tagged LDS spin; intra-block lag<=1 => <= want)
            u64 k;
            for (;;) {
                k = (lane < WPB)
                    ? __hip_atomic_load(&lkey[lane], __ATOMIC_RELAXED,
                                        __HIP_MEMORY_SCOPE_WORKGROUP)
                    : (want << 54);
                if (__all((int)((k >> 54) >= want))) break;
            }
            const u64 bk = wave_max_u64(lane < WPB ? k : 0);   // lane63 = block key (tagged)
            if (lane == 63) store_agent(&bs[g], bk);

            // poll all 16 slots (one 128-B line), one per lane-group, 2-deep pipelined:
            // keep one poll in flight so the effective poll granularity is ~half an LLC
            // round-trip instead of a full one.
            u64 v;
            {
                u64* sp = &bs[lane & 15];
                u64 vcur = load_agent(sp);
                u64 vnxt = load_agent(sp);
                int tries = 0;
                for (;;) {
                    if (__all((int)((vcur >> 54) >= want))) { v = vcur; break; }
                    vcur = vnxt;
                    vnxt = load_agent(sp);
                    if (++tries > 64) __builtin_amdgcn_s_sleep(1);
                }
            }

            // global argmax over the 16 block keys; publish to the other waves
            const u64 w = bcast_lane63(wave_max_u64(v));
            if (lane == 0)
                __hip_atomic_store(&pub, w, __ATOMIC_RELAXED,
                                   __HIP_MEMORY_SCOPE_WORKGROUP);
            cur = (int)(0x3FFFFFu - (unsigned)(w & 0x3FFFFFu));
        } else {
            // waves 1-3: spin on the seq-tagged LDS publish (no barrier)
            u64 pv;
            int tries = 0;
            for (;;) {
                pv = __hip_atomic_load(&pub, __ATOMIC_RELAXED,
                                       __HIP_MEMORY_SCOPE_WORKGROUP);
                if ((pv >> 54) >= want) break;
                if (++tries > 64) __builtin_amdgcn_s_sleep(1);
            }
            cur = (int)(0x3FFFFFu - (unsigned)(pv & 0x3FFFFFu));
        }

        cx = P[cur * 3 + 0];   // broadcast gather (batch xyz = 1.2 MB, L2-hot)
        cy = P[cur * 3 + 1];
        cz = P[cur * 3 + 2];
    }

    // ---------------- deferred output pass: 64 rows per block ----------------
    __syncthreads();                   // waves converge; curhist fully written
    if (tid < 64) {
        const int row = g * 64 + tid;  // 16 blocks x 64 rows = 1024
        const int c   = curhist[row];
        const float cm = cmap[(size_t)b * NPTS + c];
        const float x = P[c * 3 + 0], y = P[c * 3 + 1], z = P[c * 3 + 2];
        float* o = out + ((size_t)b * NPOINT + row) * 4;
        o[0] = cm;
        o[1] = x / sb;
        o[2] = y / sb;
        o[3] = z / sb;
    }
}

extern "C" void kernel_launch(void* const* d_in, const int* in_sizes, int n_in,
                              void* d_out, int out_size, void* d_ws, size_t ws_size,
                              hipStream_t stream) {
    const float* mesh = (const float*)d_in[0];
    const float* cmap = (const float*)d_in[1];
    const int* init   = (const int*)d_in[2];
    float* out = (float*)d_out;

    char* ws      = (char*)d_ws;
    float* psum   = (float*)ws;
    unsigned* pmx = (unsigned*)(ws + 4096);
    u64* slots    = (u64*)(ws + 8192);

    sum_kernel<<<dim3(256), dim3(TPB), 0, stream>>>(mesh, psum);
    max_kernel<<<dim3(256), dim3(TPB), 0, stream>>>(mesh, psum, pmx, slots);
    fps_kernel<<<dim3(256), dim3(TPB), 0, stream>>>(mesh, cmap, init, pmx, slots, out);
}